// Round 10
// baseline (1038.818 us; speedup 1.0000x reference)
//
#include <hip/hip_runtime.h>
#include <cmath>

#define NANCH 36864
#define NPRE 6000
#define NPOST 300

// ---- output (float) offsets ----
#define LOCS_OFF   0
#define SCORES_OFF 294912
#define ROIS_OFF   442368
#define RIDX_OFF   444768
#define ANCH_OFF   445368

// ---- workspace byte offsets ----
#define WT_OFF      0ull          // 9*512*512*4 = 9437184 (conv1 weights)
#define PREFIX_OFF  2097152ull    // 2*65536*4 = 524288 (inside dead WT region)
#define PREFIXM_OFF 2621440ull    // 2*65536*4 = 524288
#define SORTED_OFF  3145728ull    // 2*8192*8  = 131072
#define MASK_OFF    0ull          // reuse after fixup: 2*6000*94*8 = 9024000
#define H_OFF       9437184ull    // 2*512*4096*4  = 16777216
#define BOXES_OFF   26214400ull   // 2*36864*16    = 1179648
#define W54_OFF     26214400ull   // w54p lives in BOXES region until decode
#define KEYS_OFF    27394048ull   // 2*36864*8     = 589824
#define HIST_OFF    27983872ull   // 2*65536*4     = 524288
#define SKEYS_OFF   28631168ull   // 2*6000*8      = 96000
#define SBOXES_OFF  28727168ull   // 2*6000*16     = 192000
#define VMASK_OFF   29033856ull   // 2*94*8        = 1504

__device__ __forceinline__ void load_lds16(const float* g, float* l) {
#if __has_builtin(__builtin_amdgcn_global_load_lds)
  __builtin_amdgcn_global_load_lds(
      (const __attribute__((address_space(1))) void*)g,
      (__attribute__((address_space(3))) void*)l, 16, 0, 0);
#else
  int lane = threadIdx.x & 63;
  float4 v = *(const float4*)g;
  *(float4*)((char*)l + lane * 16) = v;
#endif
}

// =====================================================================
// prep: fused weight transposes.
// blocks 0..255  : w[co][ci][kk] -> wt[kk][ci][co]   (1024 thr as 32x32)
// blocks 256..287: loc_w/score_w -> w54p[512][64] (cols 54..63 zero)
// =====================================================================
__global__ __launch_bounds__(1024) void prep_kernel(
    const float* __restrict__ w, float* __restrict__ wt,
    const float* __restrict__ lw, const float* __restrict__ sw,
    float* __restrict__ w54p) {
  __shared__ float lds[9][32][33];
  if (blockIdx.x < 256) {
    int tx = threadIdx.x & 31;
    int ty = threadIdx.x >> 5;
    int ci0 = (blockIdx.x & 15) * 32;
    int co0 = (blockIdx.x >> 4) * 32;
    const float* src = w + ((size_t)(co0 + ty) * 512 + (ci0 + tx)) * 9;
#pragma unroll
    for (int k = 0; k < 9; k++) lds[k][tx][ty] = src[k];
    __syncthreads();
#pragma unroll
    for (int k = 0; k < 9; k++) {
      wt[((size_t)k * 512 + (ci0 + ty)) * 512 + co0 + tx] = lds[k][ty][tx];
    }
  } else {
    int t = (blockIdx.x - 256) * 1024 + threadIdx.x;   // < 32768
    int k = t >> 6, co = t & 63;
    float v = 0.f;
    if (co < 36) v = lw[(size_t)co * 512 + k];
    else if (co < 54) v = sw[(size_t)(co - 36) * 512 + k];
    w54p[t] = v;
  }
}

// =====================================================================
// conv1 (R7-proven, 538 us): 3x3 512->512 pad1 + bias + ReLU.
// Intra-block split-K: 256 thr = 2 teams of 128 (ci halves).  Per team:
// 64x x 128co tile, micro 8x x 8co (64 acc), BK=4.  Combine via LDS.
// Unified smem[10944]; all indices in bounds.
// grid = (n*64+y [128], co/128 [4]) = 512 blocks x 4 waves.
// NOTE (R8 lesson): smaller co-tiles raise occupancy but double per-fma
// overhead -> net loss.  This 128-co / 64-acc shape is the plateau.
// =====================================================================
__global__ __launch_bounds__(256) void conv1_kernel(
    const float* __restrict__ x, const float* __restrict__ wt,
    const float* __restrict__ bias, float* __restrict__ hout) {
  __shared__ __align__(16) float smem[10944];   // 43776 B
  int mb = blockIdx.x;
  int n = mb >> 6, y = mb & 63;
  int co0 = blockIdx.y << 7;
  int tid = threadIdx.x;
  int team = tid >> 7;               // 0/1 -> ci half
  int tl = tid & 127;
  int cibase = team << 8;
  float* Asb = smem + team * 864;            // 12 rows x 72
  float* Bsb = smem + 1728 + team * 4608;    // 36 rows x 128
  int tx = tl & 7, ty = tl >> 3;     // 8 x-groups x 16 co-groups
  int x0 = tx << 3;

  float acc[8][8];                   // [co j][x dx]
#pragma unroll
  for (int j = 0; j < 8; j++)
#pragma unroll
    for (int i = 0; i < 8; i++) acc[j][i] = 0.f;

  const float* xb = x + ((size_t)n << 21);

  // zero the As pads (cols 0..3, 68..71 of 12 rows); stays zero all loop.
  if (tl < 96) {
    int row = tl >> 3, c = tl & 7;
    int col = (c < 4) ? c : (64 + c);
    Asb[row * 72 + col] = 0.f;
  }

  int wv = tl >> 6;                  // team-local wave 0/1
  int lane = tl & 63;
  int lrow = lane >> 5;
  int lcol = (lane & 31) << 2;

  for (int cc = 0; cc < 256; cc += 4) {
    int ci0 = cibase + cc;
    // ---- stage A: 12 rows (4 ci x 3 yr) x 64 floats ----
    for (int t = tl; t < 192; t += 128) {
      int row = t >> 4;
      int l = t & 15;
      int ci = row / 3;
      int yr = row - ci * 3;
      int ys = y + yr - 1;
      float4 v = {0.f, 0.f, 0.f, 0.f};
      if (ys >= 0 && ys < 64)
        v = *(const float4*)&xb[(((size_t)(ci0 + ci)) << 12) + (ys << 6) + (l << 2)];
      *(float4*)&Asb[row * 72 + 4 + (l << 2)] = v;
    }
    // ---- stage B: 36 rows (kk*4+ci) x 128 co; 9 DMA per team-wave ----
    for (int i = 0; i < 9; i++) {
      int r0 = i * 4 + wv * 2;
      int row = r0 + lrow;
      int kk = row >> 2, ci = row & 3;
      const float* g = wt + (((size_t)(kk << 9)) + ci0 + ci) * 512 + co0 + lcol;
      load_lds16(g, &Bsb[r0 << 7]);
    }
    __syncthreads();
    // ---- compute: 4 ci x 3 ky x 3 kx x 64 fma ----
    for (int k = 0; k < 4; k++) {
      const float* ar = &Asb[k * 216];
#pragma unroll
      for (int ky = 0; ky < 3; ky++) {
        const float* arr = ar + ky * 72;
        float w10[10];
        w10[0] = arr[x0 + 3];
        float4 a0 = *(const float4*)&arr[x0 + 4];
        float4 a1 = *(const float4*)&arr[x0 + 8];
        w10[1] = a0.x; w10[2] = a0.y; w10[3] = a0.z; w10[4] = a0.w;
        w10[5] = a1.x; w10[6] = a1.y; w10[7] = a1.z; w10[8] = a1.w;
        w10[9] = arr[x0 + 12];
#pragma unroll
        for (int kx = 0; kx < 3; kx++) {
          int kk = ky * 3 + kx;
          const float* br = &Bsb[(((kk << 2) + k) << 7) + (ty << 3)];
          float4 b0 = *(const float4*)br;
          float4 b1 = *(const float4*)(br + 4);
          float bb[8] = {b0.x, b0.y, b0.z, b0.w, b1.x, b1.y, b1.z, b1.w};
#pragma unroll
          for (int j = 0; j < 8; j++)
#pragma unroll
            for (int dx = 0; dx < 8; dx++)
              acc[j][dx] = fmaf(w10[kx + dx], bb[j], acc[j][dx]);
        }
      }
    }
    __syncthreads();
  }

  // ---- combine: team1 -> smem[tl*68, +64), team0 adds + bias + ReLU.
  // Max index 127*68+63 = 8699 < 10944 (in bounds).
  if (team == 1) {
#pragma unroll
    for (int j = 0; j < 8; j++) {
      *(float4*)&smem[tl * 68 + (j << 3)] = *(float4*)&acc[j][0];
      *(float4*)&smem[tl * 68 + (j << 3) + 4] = *(float4*)&acc[j][4];
    }
  }
  __syncthreads();
  if (team == 0) {
#pragma unroll
    for (int j = 0; j < 8; j++) {
      int co = co0 + (ty << 3) + j;
      float bv = bias[co];
      float4 p0 = *(float4*)&smem[tl * 68 + (j << 3)];
      float4 p1 = *(float4*)&smem[tl * 68 + (j << 3) + 4];
      float4 v0, v1;
      v0.x = fmaxf((acc[j][0] + p0.x) + bv, 0.f);
      v0.y = fmaxf((acc[j][1] + p0.y) + bv, 0.f);
      v0.z = fmaxf((acc[j][2] + p0.z) + bv, 0.f);
      v0.w = fmaxf((acc[j][3] + p0.w) + bv, 0.f);
      v1.x = fmaxf((acc[j][4] + p1.x) + bv, 0.f);
      v1.y = fmaxf((acc[j][5] + p1.y) + bv, 0.f);
      v1.z = fmaxf((acc[j][6] + p1.z) + bv, 0.f);
      v1.w = fmaxf((acc[j][7] + p1.w) + bv, 0.f);
      float* o = &hout[(((size_t)(n * 512 + co)) << 12) + (y << 6) + x0];
      *(float4*)o = v0;
      *(float4*)(o + 4) = v1;
    }
  }
}

// =====================================================================
// heads v2 (proven): tiled GEMM M=64p x N=54 x K=512.
// =====================================================================
__global__ __launch_bounds__(256) void heads_kernel(
    const float* __restrict__ h, const float* __restrict__ w54p,
    const float* __restrict__ loc_b, const float* __restrict__ score_b,
    float* __restrict__ out) {
  __shared__ __align__(16) float hs[32 * 64];
  __shared__ __align__(16) float wsd[32 * 64];
  __shared__ float sacc[64 * 65];
  int n = blockIdx.x >> 6;
  int p0 = (blockIdx.x & 63) << 6;
  int tid = threadIdx.x;
  int txp = tid & 63;
  int tw = tid >> 6;
  float acc[16];
#pragma unroll
  for (int j = 0; j < 16; j++) acc[j] = 0.f;
  const float* hb = h + ((size_t)n * 512) * 4096 + p0;
  for (int k0 = 0; k0 < 512; k0 += 32) {
    for (int t = tid; t < 512; t += 256) {
      int r = t >> 4, l = (t & 15) << 2;
      *(float4*)&hs[(r << 6) + l] =
          *(const float4*)&hb[(((size_t)(k0 + r)) << 12) + l];
      *(float4*)&wsd[(r << 6) + l] =
          *(const float4*)&w54p[((k0 + r) << 6) + l];
    }
    __syncthreads();
    for (int k = 0; k < 32; k++) {
      float hv = hs[(k << 6) + txp];
      const float* wr = &wsd[(k << 6) + (tw << 4)];
#pragma unroll
      for (int u = 0; u < 4; u++) {
        float4 wv = *(const float4*)(wr + (u << 2));
        acc[u * 4 + 0] = fmaf(hv, wv.x, acc[u * 4 + 0]);
        acc[u * 4 + 1] = fmaf(hv, wv.y, acc[u * 4 + 1]);
        acc[u * 4 + 2] = fmaf(hv, wv.z, acc[u * 4 + 2]);
        acc[u * 4 + 3] = fmaf(hv, wv.w, acc[u * 4 + 3]);
      }
    }
    __syncthreads();
  }
#pragma unroll
  for (int j = 0; j < 16; j++) sacc[(tw * 16 + j) * 65 + txp] = acc[j];
  __syncthreads();
  for (int t = tid; t < 64 * 54; t += 256) {
    int p = t / 54, c = t - p * 54;
    float v = sacc[c * 65 + p];
    int gp = (n << 12) + p0 + p;
    if (c < 36) out[LOCS_OFF + (size_t)gp * 36 + c] = v + loc_b[c];
    else out[SCORES_OFF + (size_t)gp * 18 + (c - 36)] = v + score_b[c - 36];
  }
}

// =====================================================================
// Decode (anchors fused + hist fused)
// =====================================================================
__global__ void decode_kernel(const float* __restrict__ out_ro,
                              const int* __restrict__ pimh,
                              const int* __restrict__ pimw,
                              float* __restrict__ boxes,
                              unsigned long long* __restrict__ keys,
                              unsigned int* __restrict__ hist,
                              float* __restrict__ out) {
  int t = blockIdx.x * 256 + threadIdx.x;
  int n = t / NANCH, k = t - n * NANCH;
  float imh = (float)pimh[0], imw = (float)pimw[0];

  int a = k % 9, pos = k / 9;
  int jj = pos & 63, ii = pos >> 6;
  int ridx = a / 3, sidx = a % 3;
  double r = (ridx == 0) ? 0.5 : ((ridx == 1) ? 1.0 : 2.0);
  double s = (sidx == 0) ? 8.0 : ((sidx == 1) ? 16.0 : 32.0);
  double ahh = 16.0 * s * sqrt(r);
  double aww = 16.0 * s * sqrt(1.0 / r);
  float b0 = (float)(8.0 - ahh / 2.0), b1 = (float)(8.0 - aww / 2.0);
  float b2 = (float)(8.0 + ahh / 2.0), b3 = (float)(8.0 + aww / 2.0);
  float sy = (float)(ii * 16), sx = (float)(jj * 16);
  float a0 = sy + b0, a1 = sx + b1, a2 = sy + b2, a3 = sx + b3;
  if (n == 0) {
    float* o = out + ANCH_OFF + (size_t)k * 4;
    o[0] = a0; o[1] = a1; o[2] = a2; o[3] = a3;
  }

  const float* loc = out_ro + LOCS_OFF + (size_t)t * 4;
  const float* sc = out_ro + SCORES_OFF + (size_t)t * 2;
  float ah = __fsub_rn(a2, a0), aw = __fsub_rn(a3, a1);
  float acy = __fadd_rn(a0, 0.5f * ah), acx = __fadd_rn(a1, 0.5f * aw);
  float dy = loc[0], dx = loc[1], dh = loc[2], dw = loc[3];
  float cy = __fadd_rn(__fmul_rn(dy, ah), acy);
  float cx = __fadd_rn(__fmul_rn(dx, aw), acx);
  float hh = __fmul_rn(expf(dh), ah);
  float ww = __fmul_rn(expf(dw), aw);
  float y1 = __fsub_rn(cy, 0.5f * hh), x1 = __fsub_rn(cx, 0.5f * ww);
  float y2 = __fadd_rn(cy, 0.5f * hh), x2 = __fadd_rn(cx, 0.5f * ww);
  y1 = fminf(fmaxf(y1, 0.f), imh); x1 = fminf(fmaxf(x1, 0.f), imw);
  y2 = fminf(fmaxf(y2, 0.f), imh); x2 = fminf(fmaxf(x2, 0.f), imw);
  bool valid = (__fsub_rn(y2, y1) >= 16.f) && (__fsub_rn(x2, x1) >= 16.f);
  float s0 = sc[0], s1 = sc[1];
  float m = fmaxf(s0, s1);
  float e0 = expf(__fsub_rn(s0, m)), e1 = expf(__fsub_rn(s1, m));
  float fg = __fdiv_rn(e1, __fadd_rn(e0, e1));
  float score = valid ? fg : -INFINITY;
  unsigned int u = __float_as_uint(score);
  unsigned int ord = (u & 0x80000000u) ? ~u : (u | 0x80000000u);
  unsigned long long key =
      ((unsigned long long)(~ord) << 16) | (unsigned long long)(k & 0xFFFF);
  float4 b4; b4.x = y1; b4.y = x1; b4.z = y2; b4.w = x2;
  *(float4*)(boxes + (size_t)t * 4) = b4;
  keys[t] = key;
  atomicAdd(&hist[((size_t)n << 16) + (unsigned int)(key >> 32)], 1u);
}

// =====================================================================
// Full exclusive prefix over 65536 buckets (per batch), uint4-vectorized
// =====================================================================
__global__ __launch_bounds__(1024) void scanfull_kernel(
    const unsigned int* __restrict__ hist, unsigned int* __restrict__ prefix,
    unsigned int* __restrict__ prefix_mut) {
  int n = blockIdx.x;
  const uint4* h4 = (const uint4*)(hist + ((size_t)n << 16));
  uint4* pf4 = (uint4*)(prefix + ((size_t)n << 16));
  uint4* pm4 = (uint4*)(prefix_mut + ((size_t)n << 16));
  __shared__ unsigned int ps[1024];
  int tid = threadIdx.x;
  int base4 = tid << 4;
  uint4 vals[16];
  unsigned int s = 0;
#pragma unroll
  for (int i = 0; i < 16; i++) {
    vals[i] = h4[base4 + i];
    s += vals[i].x + vals[i].y + vals[i].z + vals[i].w;
  }
  ps[tid] = s;
  __syncthreads();
  for (int off = 1; off < 1024; off <<= 1) {
    unsigned int v = ps[tid];
    unsigned int add = (tid >= off) ? ps[tid - off] : 0u;
    __syncthreads();
    ps[tid] = v + add;
    __syncthreads();
  }
  unsigned int run = ps[tid] - s;
#pragma unroll
  for (int i = 0; i < 16; i++) {
    uint4 hv = vals[i];
    uint4 pv;
    pv.x = run; run += hv.x;
    pv.y = run; run += hv.y;
    pv.z = run; run += hv.z;
    pv.w = run; run += hv.w;
    pf4[base4 + i] = pv;
    pm4[base4 + i] = pv;
  }
}

// =====================================================================
// Scatter into bucket-sorted order (unordered within bucket)
// =====================================================================
__global__ void scatter_kernel(const unsigned long long* __restrict__ keys,
                               unsigned int* __restrict__ prefix_mut,
                               unsigned long long* __restrict__ sorted) {
  int t = blockIdx.x * 256 + threadIdx.x;
  int n = t / NANCH;
  unsigned long long key = keys[t];
  unsigned int b = (unsigned int)(key >> 32);
  unsigned int pos = atomicAdd(&prefix_mut[((size_t)n << 16) + b], 1u);
  if (pos < 8192) sorted[((size_t)n << 13) + pos] = key;
}

// =====================================================================
// Fixup: exact rank within bucket -> final sorted top-6000 + boxes
// =====================================================================
__global__ void fixup_kernel(const unsigned long long* __restrict__ sorted,
                             const unsigned int* __restrict__ prefix,
                             const unsigned int* __restrict__ hist,
                             const float* __restrict__ boxes,
                             unsigned long long* __restrict__ skeys,
                             float* __restrict__ sboxes) {
  int t = blockIdx.x * 256 + threadIdx.x;   // 2*7168
  int n = t / 7168;
  int s = t - n * 7168;
  const unsigned long long* srt = sorted + ((size_t)n << 13);
  unsigned long long key = srt[s];
  unsigned int hi = (unsigned int)(key >> 16);
  if (hi >= 0xFF800000u) {
    if (s < NPRE) skeys[(size_t)n * NPRE + s] = key;
    return;
  }
  unsigned int b = (unsigned int)(key >> 32);
  unsigned int st = prefix[((size_t)n << 16) + b];
  if (st >= (unsigned)NPRE) return;
  unsigned int cnt = hist[((size_t)n << 16) + b];
  unsigned int r = 0;
  if (cnt > 1) {
    for (unsigned int j = 0; j < cnt; j++) r += (srt[st + j] < key) ? 1u : 0u;
  }
  unsigned int pos = st + r;
  if (pos < (unsigned)NPRE) {
    skeys[(size_t)n * NPRE + pos] = key;
    int k = (int)(key & 0xFFFFull);
    float4 bx = *(const float4*)(boxes + (((size_t)n * NANCH) + k) * 4);
    *(float4*)(sboxes + ((size_t)n * NPRE + pos) * 4) = bx;
  }
}

// =====================================================================
// NMS phase A: pairwise suppression bitmask (+ fused validity mask)
// =====================================================================
__global__ __launch_bounds__(64) void nms_mask_kernel(
    const float* __restrict__ sboxes,
    const unsigned long long* __restrict__ skeys,
    unsigned long long* __restrict__ vmask,
    unsigned long long* __restrict__ mask) {
  int n = blockIdx.z;
  int ib = blockIdx.x, jb = blockIdx.y;
  int lane = threadIdx.x;
  __shared__ __align__(16) float jbox[64][4];
  int j = jb * 64 + lane;
  float4 bj4 = (j < NPRE)
                   ? *(const float4*)(sboxes + ((size_t)n * NPRE + j) * 4)
                   : float4{0.f, 0.f, 0.f, 0.f};
  *(float4*)jbox[lane] = bj4;
  __syncthreads();
  if (jb == 0) {
    int idx = ib * 64 + lane;
    bool ok = false;
    if (idx < NPRE) {
      unsigned int khi = (unsigned int)(skeys[(size_t)n * NPRE + idx] >> 16);
      ok = khi < 0xFF800000u;
    }
    unsigned long long m = __ballot(ok);
    if (lane == 0) vmask[(size_t)n * 94 + ib] = m;
  }
  int i = ib * 64 + lane;
  if (i >= NPRE) return;
  float4 bi = *(const float4*)(sboxes + ((size_t)n * NPRE + i) * 4);
  float ay1 = bi.x, ax1 = bi.y, ay2 = bi.z, ax2 = bi.w;
  float areaA = __fmul_rn(__fsub_rn(ay2, ay1), __fsub_rn(ax2, ax1));
  unsigned long long bits = 0ull;
#pragma unroll 8
  for (int l = 0; l < 64; l++) {
    float4 bj = *(const float4*)jbox[l];
    float ty1 = fmaxf(ay1, bj.x), tx1 = fmaxf(ax1, bj.y);
    float ty2 = fminf(ay2, bj.z), tx2 = fminf(ax2, bj.w);
    float wh0 = fmaxf(__fsub_rn(ty2, ty1), 0.f);
    float wh1 = fmaxf(__fsub_rn(tx2, tx1), 0.f);
    float inter = __fmul_rn(wh0, wh1);
    float areaB = __fmul_rn(__fsub_rn(bj.z, bj.x), __fsub_rn(bj.w, bj.y));
    float den = __fadd_rn(__fsub_rn(__fadd_rn(areaA, areaB), inter), 1e-9f);
    float iou = __fdiv_rn(inter, den);
    if (iou > 0.7f) bits |= (1ull << l);
  }
  mask[((size_t)n * NPRE + i) * 94 + jb] = bits;
}

// =====================================================================
// NMS phase B: sequential greedy reduce, one wave per batch,
// DEPTH-2 SPECULATIVE row prefetch (decisions unchanged: kept list is
// computed from the fully-updated removed mask; speculation only moves
// the memory load earlier, halving the dependent-latency chain).
// =====================================================================
__global__ __launch_bounds__(64) void nms_reduce_kernel(
    const unsigned long long* __restrict__ mask,
    const unsigned long long* __restrict__ vmask,
    const float* __restrict__ sboxes, float* __restrict__ out) {
  int n = blockIdx.x;
  int lane = threadIdx.x;
  __shared__ int kept[NPOST];
  __shared__ int s_count;

  unsigned long long rlo = ~vmask[(size_t)n * 94 + lane];
  unsigned long long rhi = (64 + lane < 94) ? ~vmask[(size_t)n * 94 + 64 + lane]
                                            : ~0ull;

  // next alive index strictly > i (i may be -1); wave-uniform result.
  auto next_alive = [&](int i) -> int {
    int c;
    unsigned long long cand;
    if (i < 0) {
      c = 0;
      cand = ~__shfl(rlo, 0);
    } else {
      c = i >> 6;
      int b = i & 63;
      unsigned long long w = (c < 64) ? __shfl(rlo, c) : __shfl(rhi, c - 64);
      cand = ~w & ((b == 63) ? 0ull : (~0ull << (b + 1)));
    }
    while (cand == 0ull) {
      c++;
      if (c >= 94) return -1;
      unsigned long long w = (c < 64) ? __shfl(rlo, c) : __shfl(rhi, c - 64);
      cand = ~w;
    }
    return (c << 6) + __builtin_ctzll(cand);
  };

  int count = 0;
  int cur = next_alive(-1);
  unsigned long long r0 = 0, r1 = 0;
  if (cur >= 0) {
    const unsigned long long* row = mask + ((size_t)n * NPRE + cur) * 94;
    r0 = row[lane];
    r1 = (64 + lane < 94) ? row[64 + lane] : 0ull;
  }
  while (cur >= 0 && count < NPOST) {
    if (lane == 0) kept[count] = cur;
    count++;
    // speculative next candidate (pre-OR of cur's row): issue its row load
    int spec = next_alive(cur);
    unsigned long long sp0 = 0, sp1 = 0;
    if (spec >= 0) {
      const unsigned long long* row = mask + ((size_t)n * NPRE + spec) * 94;
      sp0 = row[lane];
      sp1 = (64 + lane < 94) ? row[64 + lane] : 0ull;
    }
    // apply cur's suppression row
    rlo |= r0; rhi |= r1;
    if (count >= NPOST) break;
    int nxt = next_alive(cur);
    if (nxt < 0) break;
    if (nxt == spec) {          // prefetch hit (~99.7%)
      r0 = sp0; r1 = sp1;
    } else {                    // spec was suppressed by cur's row
      const unsigned long long* row = mask + ((size_t)n * NPRE + nxt) * 94;
      r0 = row[lane];
      r1 = (64 + lane < 94) ? row[64 + lane] : 0ull;
    }
    cur = nxt;
  }
  if (lane == 0) s_count = count;
  __syncthreads();
  count = s_count;

  float* rois = out + ROIS_OFF + (size_t)n * NPOST * 4;
  float* ridx = out + RIDX_OFF + (size_t)n * NPOST;
  for (int s = lane; s < NPOST; s += 64) {
    float4 v = {0.f, 0.f, 0.f, 0.f};
    if (s < count) {
      int i = kept[s];
      v = *(const float4*)(sboxes + ((size_t)n * NPRE + i) * 4);
    }
    *(float4*)(rois + (size_t)s * 4) = v;
    ridx[s] = (float)n;
  }
}

// =====================================================================
extern "C" void kernel_launch(void* const* d_in, const int* in_sizes, int n_in,
                              void* d_out, int out_size, void* d_ws,
                              size_t ws_size, hipStream_t stream) {
  const float* feat = (const float*)d_in[0];
  const float* w1 = (const float*)d_in[1];
  const float* b1 = (const float*)d_in[2];
  const float* sw = (const float*)d_in[3];
  const float* sb = (const float*)d_in[4];
  const float* lw = (const float*)d_in[5];
  const float* lb = (const float*)d_in[6];
  const int* pimh = (const int*)d_in[7];
  const int* pimw = (const int*)d_in[8];
  float* out = (float*)d_out;
  char* ws = (char*)d_ws;

  float* wt = (float*)(ws + WT_OFF);
  float* w54p = (float*)(ws + W54_OFF);
  float* hbuf = (float*)(ws + H_OFF);
  float* boxes = (float*)(ws + BOXES_OFF);
  unsigned long long* keys = (unsigned long long*)(ws + KEYS_OFF);
  unsigned int* hist = (unsigned int*)(ws + HIST_OFF);
  unsigned int* prefix = (unsigned int*)(ws + PREFIX_OFF);
  unsigned int* prefix_mut = (unsigned int*)(ws + PREFIXM_OFF);
  unsigned long long* sorted = (unsigned long long*)(ws + SORTED_OFF);
  unsigned long long* skeys = (unsigned long long*)(ws + SKEYS_OFF);
  float* sboxes = (float*)(ws + SBOXES_OFF);
  unsigned long long* vmask = (unsigned long long*)(ws + VMASK_OFF);
  unsigned long long* nmask = (unsigned long long*)(ws + MASK_OFF);

  hipMemsetAsync(ws + HIST_OFF, 0, 524288, stream);

  // w54p lives in the BOXES region: written here, consumed by heads,
  // then decode overwrites the region with boxes.
  prep_kernel<<<288, 1024, 0, stream>>>(w1, wt, lw, sw, w54p);
  conv1_kernel<<<dim3(128, 4), 256, 0, stream>>>(feat, wt, b1, hbuf);
  heads_kernel<<<128, 256, 0, stream>>>(hbuf, w54p, lb, sb, out);
  decode_kernel<<<288, 256, 0, stream>>>(out, pimh, pimw, boxes, keys, hist,
                                         out);
  scanfull_kernel<<<2, 1024, 0, stream>>>(hist, prefix, prefix_mut);
  scatter_kernel<<<288, 256, 0, stream>>>(keys, prefix_mut, sorted);
  fixup_kernel<<<56, 256, 0, stream>>>(sorted, prefix, hist, boxes, skeys,
                                       sboxes);
  // prefix/sorted dead; nmask overwrites offset 0
  nms_mask_kernel<<<dim3(94, 94, 2), 64, 0, stream>>>(sboxes, skeys, vmask,
                                                      nmask);
  nms_reduce_kernel<<<2, 64, 0, stream>>>(nmask, vmask, sboxes, out);
}

// Round 11
// 980.105 us; speedup vs baseline: 1.0599x; 1.0599x over previous
//
#include <hip/hip_runtime.h>
#include <cmath>

#define NANCH 36864
#define NPRE 6000
#define NPOST 300

// ---- output (float) offsets ----
#define LOCS_OFF   0
#define SCORES_OFF 294912
#define ROIS_OFF   442368
#define RIDX_OFF   444768
#define ANCH_OFF   445368

// ---- workspace byte offsets ----
#define WT_OFF      0ull          // 9*512*512*4 = 9437184 (conv1 weights)
#define PREFIX_OFF  2097152ull    // 2*65536*4 = 524288 (inside dead WT region)
#define PREFIXM_OFF 2621440ull    // 2*65536*4 = 524288
#define SORTED_OFF  3145728ull    // 2*8192*8  = 131072
#define MASK_OFF    0ull          // reuse after fixup: 2*6000*94*8 = 9024000
#define H_OFF       9437184ull    // 2*512*4096*4  = 16777216
#define BOXES_OFF   26214400ull   // 2*36864*16    = 1179648
#define W54_OFF     26214400ull   // w54p lives in BOXES region until decode
#define KEYS_OFF    27394048ull   // 2*36864*8     = 589824
#define HIST_OFF    27983872ull   // 2*65536*4     = 524288
#define SKEYS_OFF   28631168ull   // 2*6000*8      = 96000
#define SBOXES_OFF  28727168ull   // 2*6000*16     = 192000
#define VMASK_OFF   29033856ull   // 2*94*8        = 1504

__device__ __forceinline__ void load_lds16(const float* g, float* l) {
#if __has_builtin(__builtin_amdgcn_global_load_lds)
  __builtin_amdgcn_global_load_lds(
      (const __attribute__((address_space(1))) void*)g,
      (__attribute__((address_space(3))) void*)l, 16, 0, 0);
#else
  int lane = threadIdx.x & 63;
  float4 v = *(const float4*)g;
  *(float4*)((char*)l + lane * 16) = v;
#endif
}

// =====================================================================
// prep: fused weight transposes (R10-verified, conv1 counters unchanged)
// blocks 0..255  : w[co][ci][kk] -> wt[kk][ci][co]   (1024 thr as 32x32)
// blocks 256..287: loc_w/score_w -> w54p[512][64] (cols 54..63 zero)
// =====================================================================
__global__ __launch_bounds__(1024) void prep_kernel(
    const float* __restrict__ w, float* __restrict__ wt,
    const float* __restrict__ lw, const float* __restrict__ sw,
    float* __restrict__ w54p) {
  __shared__ float lds[9][32][33];
  if (blockIdx.x < 256) {
    int tx = threadIdx.x & 31;
    int ty = threadIdx.x >> 5;
    int ci0 = (blockIdx.x & 15) * 32;
    int co0 = (blockIdx.x >> 4) * 32;
    const float* src = w + ((size_t)(co0 + ty) * 512 + (ci0 + tx)) * 9;
#pragma unroll
    for (int k = 0; k < 9; k++) lds[k][tx][ty] = src[k];
    __syncthreads();
#pragma unroll
    for (int k = 0; k < 9; k++) {
      wt[((size_t)k * 512 + (ci0 + ty)) * 512 + co0 + tx] = lds[k][ty][tx];
    }
  } else {
    int t = (blockIdx.x - 256) * 1024 + threadIdx.x;   // < 32768
    int k = t >> 6, co = t & 63;
    float v = 0.f;
    if (co < 36) v = lw[(size_t)co * 512 + k];
    else if (co < 54) v = sw[(size_t)(co - 36) * 512 + k];
    w54p[t] = v;
  }
}

// =====================================================================
// conv1 (R7/R9-proven, ~540 us): 3x3 512->512 pad1 + bias + ReLU.
// Intra-block split-K: 256 thr = 2 teams of 128 (ci halves).  Per team:
// 64x x 128co tile, micro 8x x 8co (64 acc), BK=4.  Combine via LDS.
// Unified smem[10944]; all indices in bounds.
// grid = (n*64+y [128], co/128 [4]) = 512 blocks x 4 waves.
// NOTE (R8 lesson): smaller co-tiles raise occupancy but double per-fma
// overhead -> net loss.  This 128-co / 64-acc shape is the plateau.
// =====================================================================
__global__ __launch_bounds__(256) void conv1_kernel(
    const float* __restrict__ x, const float* __restrict__ wt,
    const float* __restrict__ bias, float* __restrict__ hout) {
  __shared__ __align__(16) float smem[10944];   // 43776 B
  int mb = blockIdx.x;
  int n = mb >> 6, y = mb & 63;
  int co0 = blockIdx.y << 7;
  int tid = threadIdx.x;
  int team = tid >> 7;               // 0/1 -> ci half
  int tl = tid & 127;
  int cibase = team << 8;
  float* Asb = smem + team * 864;            // 12 rows x 72
  float* Bsb = smem + 1728 + team * 4608;    // 36 rows x 128
  int tx = tl & 7, ty = tl >> 3;     // 8 x-groups x 16 co-groups
  int x0 = tx << 3;

  float acc[8][8];                   // [co j][x dx]
#pragma unroll
  for (int j = 0; j < 8; j++)
#pragma unroll
    for (int i = 0; i < 8; i++) acc[j][i] = 0.f;

  const float* xb = x + ((size_t)n << 21);

  // zero the As pads (cols 0..3, 68..71 of 12 rows); stays zero all loop.
  if (tl < 96) {
    int row = tl >> 3, c = tl & 7;
    int col = (c < 4) ? c : (64 + c);
    Asb[row * 72 + col] = 0.f;
  }

  int wv = tl >> 6;                  // team-local wave 0/1
  int lane = tl & 63;
  int lrow = lane >> 5;
  int lcol = (lane & 31) << 2;

  for (int cc = 0; cc < 256; cc += 4) {
    int ci0 = cibase + cc;
    // ---- stage A: 12 rows (4 ci x 3 yr) x 64 floats ----
    for (int t = tl; t < 192; t += 128) {
      int row = t >> 4;
      int l = t & 15;
      int ci = row / 3;
      int yr = row - ci * 3;
      int ys = y + yr - 1;
      float4 v = {0.f, 0.f, 0.f, 0.f};
      if (ys >= 0 && ys < 64)
        v = *(const float4*)&xb[(((size_t)(ci0 + ci)) << 12) + (ys << 6) + (l << 2)];
      *(float4*)&Asb[row * 72 + 4 + (l << 2)] = v;
    }
    // ---- stage B: 36 rows (kk*4+ci) x 128 co; 9 DMA per team-wave ----
    for (int i = 0; i < 9; i++) {
      int r0 = i * 4 + wv * 2;
      int row = r0 + lrow;
      int kk = row >> 2, ci = row & 3;
      const float* g = wt + (((size_t)(kk << 9)) + ci0 + ci) * 512 + co0 + lcol;
      load_lds16(g, &Bsb[r0 << 7]);
    }
    __syncthreads();
    // ---- compute: 4 ci x 3 ky x 3 kx x 64 fma ----
    for (int k = 0; k < 4; k++) {
      const float* ar = &Asb[k * 216];
#pragma unroll
      for (int ky = 0; ky < 3; ky++) {
        const float* arr = ar + ky * 72;
        float w10[10];
        w10[0] = arr[x0 + 3];
        float4 a0 = *(const float4*)&arr[x0 + 4];
        float4 a1 = *(const float4*)&arr[x0 + 8];
        w10[1] = a0.x; w10[2] = a0.y; w10[3] = a0.z; w10[4] = a0.w;
        w10[5] = a1.x; w10[6] = a1.y; w10[7] = a1.z; w10[8] = a1.w;
        w10[9] = arr[x0 + 12];
#pragma unroll
        for (int kx = 0; kx < 3; kx++) {
          int kk = ky * 3 + kx;
          const float* br = &Bsb[(((kk << 2) + k) << 7) + (ty << 3)];
          float4 b0 = *(const float4*)br;
          float4 b1 = *(const float4*)(br + 4);
          float bb[8] = {b0.x, b0.y, b0.z, b0.w, b1.x, b1.y, b1.z, b1.w};
#pragma unroll
          for (int j = 0; j < 8; j++)
#pragma unroll
            for (int dx = 0; dx < 8; dx++)
              acc[j][dx] = fmaf(w10[kx + dx], bb[j], acc[j][dx]);
        }
      }
    }
    __syncthreads();
  }

  // ---- combine: team1 -> smem[tl*68, +64), team0 adds + bias + ReLU.
  // Max index 127*68+63 = 8699 < 10944 (in bounds).
  if (team == 1) {
#pragma unroll
    for (int j = 0; j < 8; j++) {
      *(float4*)&smem[tl * 68 + (j << 3)] = *(float4*)&acc[j][0];
      *(float4*)&smem[tl * 68 + (j << 3) + 4] = *(float4*)&acc[j][4];
    }
  }
  __syncthreads();
  if (team == 0) {
#pragma unroll
    for (int j = 0; j < 8; j++) {
      int co = co0 + (ty << 3) + j;
      float bv = bias[co];
      float4 p0 = *(float4*)&smem[tl * 68 + (j << 3)];
      float4 p1 = *(float4*)&smem[tl * 68 + (j << 3) + 4];
      float4 v0, v1;
      v0.x = fmaxf((acc[j][0] + p0.x) + bv, 0.f);
      v0.y = fmaxf((acc[j][1] + p0.y) + bv, 0.f);
      v0.z = fmaxf((acc[j][2] + p0.z) + bv, 0.f);
      v0.w = fmaxf((acc[j][3] + p0.w) + bv, 0.f);
      v1.x = fmaxf((acc[j][4] + p1.x) + bv, 0.f);
      v1.y = fmaxf((acc[j][5] + p1.y) + bv, 0.f);
      v1.z = fmaxf((acc[j][6] + p1.z) + bv, 0.f);
      v1.w = fmaxf((acc[j][7] + p1.w) + bv, 0.f);
      float* o = &hout[(((size_t)(n * 512 + co)) << 12) + (y << 6) + x0];
      *(float4*)o = v0;
      *(float4*)(o + 4) = v1;
    }
  }
}

// =====================================================================
// heads v2 (proven): tiled GEMM M=64p x N=54 x K=512.
// =====================================================================
__global__ __launch_bounds__(256) void heads_kernel(
    const float* __restrict__ h, const float* __restrict__ w54p,
    const float* __restrict__ loc_b, const float* __restrict__ score_b,
    float* __restrict__ out) {
  __shared__ __align__(16) float hs[32 * 64];
  __shared__ __align__(16) float wsd[32 * 64];
  __shared__ float sacc[64 * 65];
  int n = blockIdx.x >> 6;
  int p0 = (blockIdx.x & 63) << 6;
  int tid = threadIdx.x;
  int txp = tid & 63;
  int tw = tid >> 6;
  float acc[16];
#pragma unroll
  for (int j = 0; j < 16; j++) acc[j] = 0.f;
  const float* hb = h + ((size_t)n * 512) * 4096 + p0;
  for (int k0 = 0; k0 < 512; k0 += 32) {
    for (int t = tid; t < 512; t += 256) {
      int r = t >> 4, l = (t & 15) << 2;
      *(float4*)&hs[(r << 6) + l] =
          *(const float4*)&hb[(((size_t)(k0 + r)) << 12) + l];
      *(float4*)&wsd[(r << 6) + l] =
          *(const float4*)&w54p[((k0 + r) << 6) + l];
    }
    __syncthreads();
    for (int k = 0; k < 32; k++) {
      float hv = hs[(k << 6) + txp];
      const float* wr = &wsd[(k << 6) + (tw << 4)];
#pragma unroll
      for (int u = 0; u < 4; u++) {
        float4 wv = *(const float4*)(wr + (u << 2));
        acc[u * 4 + 0] = fmaf(hv, wv.x, acc[u * 4 + 0]);
        acc[u * 4 + 1] = fmaf(hv, wv.y, acc[u * 4 + 1]);
        acc[u * 4 + 2] = fmaf(hv, wv.z, acc[u * 4 + 2]);
        acc[u * 4 + 3] = fmaf(hv, wv.w, acc[u * 4 + 3]);
      }
    }
    __syncthreads();
  }
#pragma unroll
  for (int j = 0; j < 16; j++) sacc[(tw * 16 + j) * 65 + txp] = acc[j];
  __syncthreads();
  for (int t = tid; t < 64 * 54; t += 256) {
    int p = t / 54, c = t - p * 54;
    float v = sacc[c * 65 + p];
    int gp = (n << 12) + p0 + p;
    if (c < 36) out[LOCS_OFF + (size_t)gp * 36 + c] = v + loc_b[c];
    else out[SCORES_OFF + (size_t)gp * 18 + (c - 36)] = v + score_b[c - 36];
  }
}

// =====================================================================
// Decode (anchors fused + hist fused)
// =====================================================================
__global__ void decode_kernel(const float* __restrict__ out_ro,
                              const int* __restrict__ pimh,
                              const int* __restrict__ pimw,
                              float* __restrict__ boxes,
                              unsigned long long* __restrict__ keys,
                              unsigned int* __restrict__ hist,
                              float* __restrict__ out) {
  int t = blockIdx.x * 256 + threadIdx.x;
  int n = t / NANCH, k = t - n * NANCH;
  float imh = (float)pimh[0], imw = (float)pimw[0];

  int a = k % 9, pos = k / 9;
  int jj = pos & 63, ii = pos >> 6;
  int ridx = a / 3, sidx = a % 3;
  double r = (ridx == 0) ? 0.5 : ((ridx == 1) ? 1.0 : 2.0);
  double s = (sidx == 0) ? 8.0 : ((sidx == 1) ? 16.0 : 32.0);
  double ahh = 16.0 * s * sqrt(r);
  double aww = 16.0 * s * sqrt(1.0 / r);
  float b0 = (float)(8.0 - ahh / 2.0), b1 = (float)(8.0 - aww / 2.0);
  float b2 = (float)(8.0 + ahh / 2.0), b3 = (float)(8.0 + aww / 2.0);
  float sy = (float)(ii * 16), sx = (float)(jj * 16);
  float a0 = sy + b0, a1 = sx + b1, a2 = sy + b2, a3 = sx + b3;
  if (n == 0) {
    float* o = out + ANCH_OFF + (size_t)k * 4;
    o[0] = a0; o[1] = a1; o[2] = a2; o[3] = a3;
  }

  const float* loc = out_ro + LOCS_OFF + (size_t)t * 4;
  const float* sc = out_ro + SCORES_OFF + (size_t)t * 2;
  float ah = __fsub_rn(a2, a0), aw = __fsub_rn(a3, a1);
  float acy = __fadd_rn(a0, 0.5f * ah), acx = __fadd_rn(a1, 0.5f * aw);
  float dy = loc[0], dx = loc[1], dh = loc[2], dw = loc[3];
  float cy = __fadd_rn(__fmul_rn(dy, ah), acy);
  float cx = __fadd_rn(__fmul_rn(dx, aw), acx);
  float hh = __fmul_rn(expf(dh), ah);
  float ww = __fmul_rn(expf(dw), aw);
  float y1 = __fsub_rn(cy, 0.5f * hh), x1 = __fsub_rn(cx, 0.5f * ww);
  float y2 = __fadd_rn(cy, 0.5f * hh), x2 = __fadd_rn(cx, 0.5f * ww);
  y1 = fminf(fmaxf(y1, 0.f), imh); x1 = fminf(fmaxf(x1, 0.f), imw);
  y2 = fminf(fmaxf(y2, 0.f), imh); x2 = fminf(fmaxf(x2, 0.f), imw);
  bool valid = (__fsub_rn(y2, y1) >= 16.f) && (__fsub_rn(x2, x1) >= 16.f);
  float s0 = sc[0], s1 = sc[1];
  float m = fmaxf(s0, s1);
  float e0 = expf(__fsub_rn(s0, m)), e1 = expf(__fsub_rn(s1, m));
  float fg = __fdiv_rn(e1, __fadd_rn(e0, e1));
  float score = valid ? fg : -INFINITY;
  unsigned int u = __float_as_uint(score);
  unsigned int ord = (u & 0x80000000u) ? ~u : (u | 0x80000000u);
  unsigned long long key =
      ((unsigned long long)(~ord) << 16) | (unsigned long long)(k & 0xFFFF);
  float4 b4; b4.x = y1; b4.y = x1; b4.z = y2; b4.w = x2;
  *(float4*)(boxes + (size_t)t * 4) = b4;
  keys[t] = key;
  atomicAdd(&hist[((size_t)n << 16) + (unsigned int)(key >> 32)], 1u);
}

// =====================================================================
// Full exclusive prefix over 65536 buckets (per batch), uint4-vectorized
// =====================================================================
__global__ __launch_bounds__(1024) void scanfull_kernel(
    const unsigned int* __restrict__ hist, unsigned int* __restrict__ prefix,
    unsigned int* __restrict__ prefix_mut) {
  int n = blockIdx.x;
  const uint4* h4 = (const uint4*)(hist + ((size_t)n << 16));
  uint4* pf4 = (uint4*)(prefix + ((size_t)n << 16));
  uint4* pm4 = (uint4*)(prefix_mut + ((size_t)n << 16));
  __shared__ unsigned int ps[1024];
  int tid = threadIdx.x;
  int base4 = tid << 4;
  uint4 vals[16];
  unsigned int s = 0;
#pragma unroll
  for (int i = 0; i < 16; i++) {
    vals[i] = h4[base4 + i];
    s += vals[i].x + vals[i].y + vals[i].z + vals[i].w;
  }
  ps[tid] = s;
  __syncthreads();
  for (int off = 1; off < 1024; off <<= 1) {
    unsigned int v = ps[tid];
    unsigned int add = (tid >= off) ? ps[tid - off] : 0u;
    __syncthreads();
    ps[tid] = v + add;
    __syncthreads();
  }
  unsigned int run = ps[tid] - s;
#pragma unroll
  for (int i = 0; i < 16; i++) {
    uint4 hv = vals[i];
    uint4 pv;
    pv.x = run; run += hv.x;
    pv.y = run; run += hv.y;
    pv.z = run; run += hv.z;
    pv.w = run; run += hv.w;
    pf4[base4 + i] = pv;
    pm4[base4 + i] = pv;
  }
}

// =====================================================================
// Scatter into bucket-sorted order (unordered within bucket)
// =====================================================================
__global__ void scatter_kernel(const unsigned long long* __restrict__ keys,
                               unsigned int* __restrict__ prefix_mut,
                               unsigned long long* __restrict__ sorted) {
  int t = blockIdx.x * 256 + threadIdx.x;
  int n = t / NANCH;
  unsigned long long key = keys[t];
  unsigned int b = (unsigned int)(key >> 32);
  unsigned int pos = atomicAdd(&prefix_mut[((size_t)n << 16) + b], 1u);
  if (pos < 8192) sorted[((size_t)n << 13) + pos] = key;
}

// =====================================================================
// Fixup: exact rank within bucket -> final sorted top-6000 + boxes
// =====================================================================
__global__ void fixup_kernel(const unsigned long long* __restrict__ sorted,
                             const unsigned int* __restrict__ prefix,
                             const unsigned int* __restrict__ hist,
                             const float* __restrict__ boxes,
                             unsigned long long* __restrict__ skeys,
                             float* __restrict__ sboxes) {
  int t = blockIdx.x * 256 + threadIdx.x;   // 2*7168
  int n = t / 7168;
  int s = t - n * 7168;
  const unsigned long long* srt = sorted + ((size_t)n << 13);
  unsigned long long key = srt[s];
  unsigned int hi = (unsigned int)(key >> 16);
  if (hi >= 0xFF800000u) {
    if (s < NPRE) skeys[(size_t)n * NPRE + s] = key;
    return;
  }
  unsigned int b = (unsigned int)(key >> 32);
  unsigned int st = prefix[((size_t)n << 16) + b];
  if (st >= (unsigned)NPRE) return;
  unsigned int cnt = hist[((size_t)n << 16) + b];
  unsigned int r = 0;
  if (cnt > 1) {
    for (unsigned int j = 0; j < cnt; j++) r += (srt[st + j] < key) ? 1u : 0u;
  }
  unsigned int pos = st + r;
  if (pos < (unsigned)NPRE) {
    skeys[(size_t)n * NPRE + pos] = key;
    int k = (int)(key & 0xFFFFull);
    float4 bx = *(const float4*)(boxes + (((size_t)n * NANCH) + k) * 4);
    *(float4*)(sboxes + ((size_t)n * NPRE + pos) * 4) = bx;
  }
}

// =====================================================================
// NMS phase A: pairwise suppression bitmask (+ fused validity mask)
// =====================================================================
__global__ __launch_bounds__(64) void nms_mask_kernel(
    const float* __restrict__ sboxes,
    const unsigned long long* __restrict__ skeys,
    unsigned long long* __restrict__ vmask,
    unsigned long long* __restrict__ mask) {
  int n = blockIdx.z;
  int ib = blockIdx.x, jb = blockIdx.y;
  int lane = threadIdx.x;
  __shared__ __align__(16) float jbox[64][4];
  int j = jb * 64 + lane;
  float4 bj4 = (j < NPRE)
                   ? *(const float4*)(sboxes + ((size_t)n * NPRE + j) * 4)
                   : float4{0.f, 0.f, 0.f, 0.f};
  *(float4*)jbox[lane] = bj4;
  __syncthreads();
  if (jb == 0) {
    int idx = ib * 64 + lane;
    bool ok = false;
    if (idx < NPRE) {
      unsigned int khi = (unsigned int)(skeys[(size_t)n * NPRE + idx] >> 16);
      ok = khi < 0xFF800000u;
    }
    unsigned long long m = __ballot(ok);
    if (lane == 0) vmask[(size_t)n * 94 + ib] = m;
  }
  int i = ib * 64 + lane;
  if (i >= NPRE) return;
  float4 bi = *(const float4*)(sboxes + ((size_t)n * NPRE + i) * 4);
  float ay1 = bi.x, ax1 = bi.y, ay2 = bi.z, ax2 = bi.w;
  float areaA = __fmul_rn(__fsub_rn(ay2, ay1), __fsub_rn(ax2, ax1));
  unsigned long long bits = 0ull;
#pragma unroll 8
  for (int l = 0; l < 64; l++) {
    float4 bj = *(const float4*)jbox[l];
    float ty1 = fmaxf(ay1, bj.x), tx1 = fmaxf(ax1, bj.y);
    float ty2 = fminf(ay2, bj.z), tx2 = fminf(ax2, bj.w);
    float wh0 = fmaxf(__fsub_rn(ty2, ty1), 0.f);
    float wh1 = fmaxf(__fsub_rn(tx2, tx1), 0.f);
    float inter = __fmul_rn(wh0, wh1);
    float areaB = __fmul_rn(__fsub_rn(bj.z, bj.x), __fsub_rn(bj.w, bj.y));
    float den = __fadd_rn(__fsub_rn(__fadd_rn(areaA, areaB), inter), 1e-9f);
    float iou = __fdiv_rn(inter, den);
    if (iou > 0.7f) bits |= (1ull << l);
  }
  mask[((size_t)n * NPRE + i) * 94 + jb] = bits;
}

// =====================================================================
// NMS phase B (R9-proven): sequential greedy reduce, one wave per batch
// =====================================================================
__global__ __launch_bounds__(64) void nms_reduce_kernel(
    const unsigned long long* __restrict__ mask,
    const unsigned long long* __restrict__ vmask,
    const float* __restrict__ sboxes, float* __restrict__ out) {
  int n = blockIdx.x;
  int lane = threadIdx.x;
  __shared__ int kept[NPOST];
  __shared__ int s_count;

  unsigned long long rlo = ~vmask[(size_t)n * 94 + lane];
  unsigned long long rhi = (64 + lane < 94) ? ~vmask[(size_t)n * 94 + 64 + lane]
                                            : ~0ull;
  int count = 0;
  for (int c = 0; c < 94 && count < NPOST; c++) {
    unsigned long long curw =
        (c < 64) ? __shfl(rlo, c) : __shfl(rhi, c - 64);
    unsigned long long cand = ~curw;
    while (cand != 0ull && count < NPOST) {
      int b = __builtin_ctzll(cand);
      int i = c * 64 + b;
      if (lane == 0) kept[count] = i;
      count++;
      const unsigned long long* row = mask + ((size_t)n * NPRE + i) * 94;
      unsigned long long r0 = row[lane];
      unsigned long long r1 = (64 + lane < 94) ? row[64 + lane] : 0ull;
      rlo |= r0; rhi |= r1;
      curw = (c < 64) ? __shfl(rlo, c) : __shfl(rhi, c - 64);
      cand = ~curw;
      cand &= (b == 63) ? 0ull : (~0ull << (b + 1));
    }
  }
  if (lane == 0) s_count = count;
  __syncthreads();
  count = s_count;

  float* rois = out + ROIS_OFF + (size_t)n * NPOST * 4;
  float* ridx = out + RIDX_OFF + (size_t)n * NPOST;
  for (int s = lane; s < NPOST; s += 64) {
    float4 v = {0.f, 0.f, 0.f, 0.f};
    if (s < count) {
      int i = kept[s];
      v = *(const float4*)(sboxes + ((size_t)n * NPRE + i) * 4);
    }
    *(float4*)(rois + (size_t)s * 4) = v;
    ridx[s] = (float)n;
  }
}

// =====================================================================
extern "C" void kernel_launch(void* const* d_in, const int* in_sizes, int n_in,
                              void* d_out, int out_size, void* d_ws,
                              size_t ws_size, hipStream_t stream) {
  const float* feat = (const float*)d_in[0];
  const float* w1 = (const float*)d_in[1];
  const float* b1 = (const float*)d_in[2];
  const float* sw = (const float*)d_in[3];
  const float* sb = (const float*)d_in[4];
  const float* lw = (const float*)d_in[5];
  const float* lb = (const float*)d_in[6];
  const int* pimh = (const int*)d_in[7];
  const int* pimw = (const int*)d_in[8];
  float* out = (float*)d_out;
  char* ws = (char*)d_ws;

  float* wt = (float*)(ws + WT_OFF);
  float* w54p = (float*)(ws + W54_OFF);
  float* hbuf = (float*)(ws + H_OFF);
  float* boxes = (float*)(ws + BOXES_OFF);
  unsigned long long* keys = (unsigned long long*)(ws + KEYS_OFF);
  unsigned int* hist = (unsigned int*)(ws + HIST_OFF);
  unsigned int* prefix = (unsigned int*)(ws + PREFIX_OFF);
  unsigned int* prefix_mut = (unsigned int*)(ws + PREFIXM_OFF);
  unsigned long long* sorted = (unsigned long long*)(ws + SORTED_OFF);
  unsigned long long* skeys = (unsigned long long*)(ws + SKEYS_OFF);
  float* sboxes = (float*)(ws + SBOXES_OFF);
  unsigned long long* vmask = (unsigned long long*)(ws + VMASK_OFF);
  unsigned long long* nmask = (unsigned long long*)(ws + MASK_OFF);

  hipMemsetAsync(ws + HIST_OFF, 0, 524288, stream);

  // w54p lives in the BOXES region: written here, consumed by heads,
  // then decode overwrites the region with boxes.
  prep_kernel<<<288, 1024, 0, stream>>>(w1, wt, lw, sw, w54p);
  conv1_kernel<<<dim3(128, 4), 256, 0, stream>>>(feat, wt, b1, hbuf);
  heads_kernel<<<128, 256, 0, stream>>>(hbuf, w54p, lb, sb, out);
  decode_kernel<<<288, 256, 0, stream>>>(out, pimh, pimw, boxes, keys, hist,
                                         out);
  scanfull_kernel<<<2, 1024, 0, stream>>>(hist, prefix, prefix_mut);
  scatter_kernel<<<288, 256, 0, stream>>>(keys, prefix_mut, sorted);
  fixup_kernel<<<56, 256, 0, stream>>>(sorted, prefix, hist, boxes, skeys,
                                       sboxes);
  // prefix/sorted dead; nmask overwrites offset 0
  nms_mask_kernel<<<dim3(94, 94, 2), 64, 0, stream>>>(sboxes, skeys, vmask,
                                                      nmask);
  nms_reduce_kernel<<<2, 64, 0, stream>>>(nmask, vmask, sboxes, out);
}

// Round 12
// 970.816 us; speedup vs baseline: 1.0700x; 1.0096x over previous
//
#include <hip/hip_runtime.h>
#include <cmath>

#define NANCH 36864
#define NPRE 6000
#define NPOST 300

// ---- output (float) offsets ----
#define LOCS_OFF   0
#define SCORES_OFF 294912
#define ROIS_OFF   442368
#define RIDX_OFF   444768
#define ANCH_OFF   445368

// ---- workspace byte offsets ----
#define WT_OFF      0ull          // 9*512*512*4 = 9437184 (conv1 weights)
#define PREFIX_OFF  2097152ull    // 2*65536*4 = 524288 (inside dead WT region)
#define PREFIXM_OFF 2621440ull    // 2*65536*4 = 524288
#define SORTED_OFF  3145728ull    // 2*8192*8  = 131072
#define MASK_OFF    0ull          // reuse after fixup: 2*6000*94*8 = 9024000
#define H_OFF       9437184ull    // 2*512*4096*4  = 16777216
#define BOXES_OFF   26214400ull   // 2*36864*16    = 1179648
#define W54_OFF     26214400ull   // w54p lives in BOXES region until decode
#define KEYS_OFF    27394048ull   // 2*36864*8     = 589824
#define HIST_OFF    27983872ull   // 2*65536*4     = 524288
#define SKEYS_OFF   28631168ull   // 2*6000*8      = 96000
#define SBOXES_OFF  28727168ull   // 2*6000*16     = 192000
#define VMASK_OFF   29033856ull   // 2*94*8        = 1504

__device__ __forceinline__ void load_lds16(const float* g, float* l) {
#if __has_builtin(__builtin_amdgcn_global_load_lds)
  __builtin_amdgcn_global_load_lds(
      (const __attribute__((address_space(1))) void*)g,
      (__attribute__((address_space(3))) void*)l, 16, 0, 0);
#else
  int lane = threadIdx.x & 63;
  float4 v = *(const float4*)g;
  *(float4*)((char*)l + lane * 16) = v;
#endif
}

// =====================================================================
// prep: fused weight transposes (R10/R11-verified)
// blocks 0..255  : w[co][ci][kk] -> wt[kk][ci][co]   (1024 thr as 32x32)
// blocks 256..287: loc_w/score_w -> w54p[512][64] (cols 54..63 zero)
// =====================================================================
__global__ __launch_bounds__(1024) void prep_kernel(
    const float* __restrict__ w, float* __restrict__ wt,
    const float* __restrict__ lw, const float* __restrict__ sw,
    float* __restrict__ w54p) {
  __shared__ float lds[9][32][33];
  if (blockIdx.x < 256) {
    int tx = threadIdx.x & 31;
    int ty = threadIdx.x >> 5;
    int ci0 = (blockIdx.x & 15) * 32;
    int co0 = (blockIdx.x >> 4) * 32;
    const float* src = w + ((size_t)(co0 + ty) * 512 + (ci0 + tx)) * 9;
#pragma unroll
    for (int k = 0; k < 9; k++) lds[k][tx][ty] = src[k];
    __syncthreads();
#pragma unroll
    for (int k = 0; k < 9; k++) {
      wt[((size_t)k * 512 + (ci0 + ty)) * 512 + co0 + tx] = lds[k][ty][tx];
    }
  } else {
    int t = (blockIdx.x - 256) * 1024 + threadIdx.x;   // < 32768
    int k = t >> 6, co = t & 63;
    float v = 0.f;
    if (co < 36) v = lw[(size_t)co * 512 + k];
    else if (co < 54) v = sw[(size_t)(co - 36) * 512 + k];
    w54p[t] = v;
  }
}

// =====================================================================
// conv1 v9: 3x3 512->512 pad1 + bias + ReLU.
// Same 2-team split-K / 64-acc / BK=4 structure as R7/R9/R11 (proven),
// but A-staging now via global_load_lds DMA (no VGPR round-trip):
//  - As layout padless [yr][ci][64]; one wave-DMA per yr batch (4 rows).
//  - out-of-range-ys rows (y=0 / y=63 blocks only) zeroed once, never
//    DMA'd -> stay zero (uniform branch).
//  - missing x-pads handled by tx==0 / tx==7 cndmask (same 0.f values).
// Operand values + fma order identical to R11 -> bit-identical h.
// smem[10752] = As 2x768 + Bs 2x4608; combine scratch needs 8704 <= 10752.
// grid = (n*64+y [128], co/128 [4]) = 512 blocks x 4 waves.
// =====================================================================
__global__ __launch_bounds__(256) void conv1_kernel(
    const float* __restrict__ x, const float* __restrict__ wt,
    const float* __restrict__ bias, float* __restrict__ hout) {
  __shared__ __align__(16) float smem[10752];   // 43008 B
  int mb = blockIdx.x;
  int n = mb >> 6, y = mb & 63;
  int co0 = blockIdx.y << 7;
  int tid = threadIdx.x;
  int team = tid >> 7;               // 0/1 -> ci half
  int tl = tid & 127;
  int cibase = team << 8;
  float* Asb = smem + team * 768;            // 12 rows x 64, [yr*4+ci][64]
  float* Bsb = smem + 1536 + team * 4608;    // 36 rows x 128
  int tx = tl & 7, ty = tl >> 3;     // 8 x-groups x 16 co-groups
  int x0 = tx << 3;

  float acc[8][8];                   // [co j][x dx]
#pragma unroll
  for (int j = 0; j < 8; j++)
#pragma unroll
    for (int i = 0; i < 8; i++) acc[j][i] = 0.f;

  const float* xb = x + ((size_t)n << 21);

  // zero out-of-range yr batches once (never DMA'd afterwards)
  if (y == 0) {
    for (int t2 = tl; t2 < 256; t2 += 128) Asb[t2] = 0.f;          // yr=0
  }
  if (y == 63) {
    for (int t2 = tl; t2 < 256; t2 += 128) Asb[512 + t2] = 0.f;    // yr=2
  }

  int wv = tl >> 6;                  // team-local wave 0/1
  int lane = tl & 63;
  int lrow = lane >> 5;
  int lcol = (lane & 31) << 2;
  int aci = lane >> 4;               // A-DMA: ci row within batch (0..3)
  int aoff = (lane & 15) << 2;       // A-DMA: float offset within row

  for (int cc = 0; cc < 256; cc += 4) {
    int ci0 = cibase + cc;
    // ---- stage A via DMA: up to 3 batches (yr) x 4 ci-rows x 64 fl ----
    for (int yr = wv; yr < 3; yr += 2) {
      int ys = y + yr - 1;
      if (ys >= 0 && ys < 64) {      // uniform per block
        const float* g =
            xb + (((size_t)(ci0 + aci)) << 12) + (ys << 6) + aoff;
        load_lds16(g, &Asb[yr << 8]);
      }
    }
    // ---- stage B: 36 rows (kk*4+ci) x 128 co; 9 DMA per team-wave ----
    for (int i = 0; i < 9; i++) {
      int r0 = i * 4 + wv * 2;
      int row = r0 + lrow;
      int kk = row >> 2, ci = row & 3;
      const float* g = wt + (((size_t)(kk << 9)) + ci0 + ci) * 512 + co0 + lcol;
      load_lds16(g, &Bsb[r0 << 7]);
    }
    __syncthreads();
    // ---- compute: 4 ci x 3 ky x 3 kx x 64 fma (order identical) ----
    for (int k = 0; k < 4; k++) {
#pragma unroll
      for (int ky = 0; ky < 3; ky++) {
        const float* arr = &Asb[((ky << 2) + k) << 6];
        float w10[10];
        w10[0] = (tx == 0) ? 0.f : arr[x0 - 1];
        float4 a0 = *(const float4*)&arr[x0];
        float4 a1 = *(const float4*)&arr[x0 + 4];
        w10[1] = a0.x; w10[2] = a0.y; w10[3] = a0.z; w10[4] = a0.w;
        w10[5] = a1.x; w10[6] = a1.y; w10[7] = a1.z; w10[8] = a1.w;
        w10[9] = (tx == 7) ? 0.f : arr[x0 + 8];
#pragma unroll
        for (int kx = 0; kx < 3; kx++) {
          int kk = ky * 3 + kx;
          const float* br = &Bsb[(((kk << 2) + k) << 7) + (ty << 3)];
          float4 b0 = *(const float4*)br;
          float4 b1 = *(const float4*)(br + 4);
          float bb[8] = {b0.x, b0.y, b0.z, b0.w, b1.x, b1.y, b1.z, b1.w};
#pragma unroll
          for (int j = 0; j < 8; j++)
#pragma unroll
            for (int dx = 0; dx < 8; dx++)
              acc[j][dx] = fmaf(w10[kx + dx], bb[j], acc[j][dx]);
        }
      }
    }
    __syncthreads();
  }

  // ---- combine: team1 -> smem[tl*68, +64), team0 adds + bias + ReLU.
  // Max index 127*68+63 = 8699 < 10752 (in bounds).
  if (team == 1) {
#pragma unroll
    for (int j = 0; j < 8; j++) {
      *(float4*)&smem[tl * 68 + (j << 3)] = *(float4*)&acc[j][0];
      *(float4*)&smem[tl * 68 + (j << 3) + 4] = *(float4*)&acc[j][4];
    }
  }
  __syncthreads();
  if (team == 0) {
#pragma unroll
    for (int j = 0; j < 8; j++) {
      int co = co0 + (ty << 3) + j;
      float bv = bias[co];
      float4 p0 = *(float4*)&smem[tl * 68 + (j << 3)];
      float4 p1 = *(float4*)&smem[tl * 68 + (j << 3) + 4];
      float4 v0, v1;
      v0.x = fmaxf((acc[j][0] + p0.x) + bv, 0.f);
      v0.y = fmaxf((acc[j][1] + p0.y) + bv, 0.f);
      v0.z = fmaxf((acc[j][2] + p0.z) + bv, 0.f);
      v0.w = fmaxf((acc[j][3] + p0.w) + bv, 0.f);
      v1.x = fmaxf((acc[j][4] + p1.x) + bv, 0.f);
      v1.y = fmaxf((acc[j][5] + p1.y) + bv, 0.f);
      v1.z = fmaxf((acc[j][6] + p1.z) + bv, 0.f);
      v1.w = fmaxf((acc[j][7] + p1.w) + bv, 0.f);
      float* o = &hout[(((size_t)(n * 512 + co)) << 12) + (y << 6) + x0];
      *(float4*)o = v0;
      *(float4*)(o + 4) = v1;
    }
  }
}

// =====================================================================
// heads v2 (proven): tiled GEMM M=64p x N=54 x K=512.
// =====================================================================
__global__ __launch_bounds__(256) void heads_kernel(
    const float* __restrict__ h, const float* __restrict__ w54p,
    const float* __restrict__ loc_b, const float* __restrict__ score_b,
    float* __restrict__ out) {
  __shared__ __align__(16) float hs[32 * 64];
  __shared__ __align__(16) float wsd[32 * 64];
  __shared__ float sacc[64 * 65];
  int n = blockIdx.x >> 6;
  int p0 = (blockIdx.x & 63) << 6;
  int tid = threadIdx.x;
  int txp = tid & 63;
  int tw = tid >> 6;
  float acc[16];
#pragma unroll
  for (int j = 0; j < 16; j++) acc[j] = 0.f;
  const float* hb = h + ((size_t)n * 512) * 4096 + p0;
  for (int k0 = 0; k0 < 512; k0 += 32) {
    for (int t = tid; t < 512; t += 256) {
      int r = t >> 4, l = (t & 15) << 2;
      *(float4*)&hs[(r << 6) + l] =
          *(const float4*)&hb[(((size_t)(k0 + r)) << 12) + l];
      *(float4*)&wsd[(r << 6) + l] =
          *(const float4*)&w54p[((k0 + r) << 6) + l];
    }
    __syncthreads();
    for (int k = 0; k < 32; k++) {
      float hv = hs[(k << 6) + txp];
      const float* wr = &wsd[(k << 6) + (tw << 4)];
#pragma unroll
      for (int u = 0; u < 4; u++) {
        float4 wv = *(const float4*)(wr + (u << 2));
        acc[u * 4 + 0] = fmaf(hv, wv.x, acc[u * 4 + 0]);
        acc[u * 4 + 1] = fmaf(hv, wv.y, acc[u * 4 + 1]);
        acc[u * 4 + 2] = fmaf(hv, wv.z, acc[u * 4 + 2]);
        acc[u * 4 + 3] = fmaf(hv, wv.w, acc[u * 4 + 3]);
      }
    }
    __syncthreads();
  }
#pragma unroll
  for (int j = 0; j < 16; j++) sacc[(tw * 16 + j) * 65 + txp] = acc[j];
  __syncthreads();
  for (int t = tid; t < 64 * 54; t += 256) {
    int p = t / 54, c = t - p * 54;
    float v = sacc[c * 65 + p];
    int gp = (n << 12) + p0 + p;
    if (c < 36) out[LOCS_OFF + (size_t)gp * 36 + c] = v + loc_b[c];
    else out[SCORES_OFF + (size_t)gp * 18 + (c - 36)] = v + score_b[c - 36];
  }
}

// =====================================================================
// Decode (anchors fused + hist fused)
// =====================================================================
__global__ void decode_kernel(const float* __restrict__ out_ro,
                              const int* __restrict__ pimh,
                              const int* __restrict__ pimw,
                              float* __restrict__ boxes,
                              unsigned long long* __restrict__ keys,
                              unsigned int* __restrict__ hist,
                              float* __restrict__ out) {
  int t = blockIdx.x * 256 + threadIdx.x;
  int n = t / NANCH, k = t - n * NANCH;
  float imh = (float)pimh[0], imw = (float)pimw[0];

  int a = k % 9, pos = k / 9;
  int jj = pos & 63, ii = pos >> 6;
  int ridx = a / 3, sidx = a % 3;
  double r = (ridx == 0) ? 0.5 : ((ridx == 1) ? 1.0 : 2.0);
  double s = (sidx == 0) ? 8.0 : ((sidx == 1) ? 16.0 : 32.0);
  double ahh = 16.0 * s * sqrt(r);
  double aww = 16.0 * s * sqrt(1.0 / r);
  float b0 = (float)(8.0 - ahh / 2.0), b1 = (float)(8.0 - aww / 2.0);
  float b2 = (float)(8.0 + ahh / 2.0), b3 = (float)(8.0 + aww / 2.0);
  float sy = (float)(ii * 16), sx = (float)(jj * 16);
  float a0 = sy + b0, a1 = sx + b1, a2 = sy + b2, a3 = sx + b3;
  if (n == 0) {
    float* o = out + ANCH_OFF + (size_t)k * 4;
    o[0] = a0; o[1] = a1; o[2] = a2; o[3] = a3;
  }

  const float* loc = out_ro + LOCS_OFF + (size_t)t * 4;
  const float* sc = out_ro + SCORES_OFF + (size_t)t * 2;
  float ah = __fsub_rn(a2, a0), aw = __fsub_rn(a3, a1);
  float acy = __fadd_rn(a0, 0.5f * ah), acx = __fadd_rn(a1, 0.5f * aw);
  float dy = loc[0], dx = loc[1], dh = loc[2], dw = loc[3];
  float cy = __fadd_rn(__fmul_rn(dy, ah), acy);
  float cx = __fadd_rn(__fmul_rn(dx, aw), acx);
  float hh = __fmul_rn(expf(dh), ah);
  float ww = __fmul_rn(expf(dw), aw);
  float y1 = __fsub_rn(cy, 0.5f * hh), x1 = __fsub_rn(cx, 0.5f * ww);
  float y2 = __fadd_rn(cy, 0.5f * hh), x2 = __fadd_rn(cx, 0.5f * ww);
  y1 = fminf(fmaxf(y1, 0.f), imh); x1 = fminf(fmaxf(x1, 0.f), imw);
  y2 = fminf(fmaxf(y2, 0.f), imh); x2 = fminf(fmaxf(x2, 0.f), imw);
  bool valid = (__fsub_rn(y2, y1) >= 16.f) && (__fsub_rn(x2, x1) >= 16.f);
  float s0 = sc[0], s1 = sc[1];
  float m = fmaxf(s0, s1);
  float e0 = expf(__fsub_rn(s0, m)), e1 = expf(__fsub_rn(s1, m));
  float fg = __fdiv_rn(e1, __fadd_rn(e0, e1));
  float score = valid ? fg : -INFINITY;
  unsigned int u = __float_as_uint(score);
  unsigned int ord = (u & 0x80000000u) ? ~u : (u | 0x80000000u);
  unsigned long long key =
      ((unsigned long long)(~ord) << 16) | (unsigned long long)(k & 0xFFFF);
  float4 b4; b4.x = y1; b4.y = x1; b4.z = y2; b4.w = x2;
  *(float4*)(boxes + (size_t)t * 4) = b4;
  keys[t] = key;
  atomicAdd(&hist[((size_t)n << 16) + (unsigned int)(key >> 32)], 1u);
}

// =====================================================================
// Full exclusive prefix over 65536 buckets (per batch), uint4-vectorized
// =====================================================================
__global__ __launch_bounds__(1024) void scanfull_kernel(
    const unsigned int* __restrict__ hist, unsigned int* __restrict__ prefix,
    unsigned int* __restrict__ prefix_mut) {
  int n = blockIdx.x;
  const uint4* h4 = (const uint4*)(hist + ((size_t)n << 16));
  uint4* pf4 = (uint4*)(prefix + ((size_t)n << 16));
  uint4* pm4 = (uint4*)(prefix_mut + ((size_t)n << 16));
  __shared__ unsigned int ps[1024];
  int tid = threadIdx.x;
  int base4 = tid << 4;
  uint4 vals[16];
  unsigned int s = 0;
#pragma unroll
  for (int i = 0; i < 16; i++) {
    vals[i] = h4[base4 + i];
    s += vals[i].x + vals[i].y + vals[i].z + vals[i].w;
  }
  ps[tid] = s;
  __syncthreads();
  for (int off = 1; off < 1024; off <<= 1) {
    unsigned int v = ps[tid];
    unsigned int add = (tid >= off) ? ps[tid - off] : 0u;
    __syncthreads();
    ps[tid] = v + add;
    __syncthreads();
  }
  unsigned int run = ps[tid] - s;
#pragma unroll
  for (int i = 0; i < 16; i++) {
    uint4 hv = vals[i];
    uint4 pv;
    pv.x = run; run += hv.x;
    pv.y = run; run += hv.y;
    pv.z = run; run += hv.z;
    pv.w = run; run += hv.w;
    pf4[base4 + i] = pv;
    pm4[base4 + i] = pv;
  }
}

// =====================================================================
// Scatter into bucket-sorted order (unordered within bucket)
// =====================================================================
__global__ void scatter_kernel(const unsigned long long* __restrict__ keys,
                               unsigned int* __restrict__ prefix_mut,
                               unsigned long long* __restrict__ sorted) {
  int t = blockIdx.x * 256 + threadIdx.x;
  int n = t / NANCH;
  unsigned long long key = keys[t];
  unsigned int b = (unsigned int)(key >> 32);
  unsigned int pos = atomicAdd(&prefix_mut[((size_t)n << 16) + b], 1u);
  if (pos < 8192) sorted[((size_t)n << 13) + pos] = key;
}

// =====================================================================
// Fixup: exact rank within bucket -> final sorted top-6000 + boxes
// =====================================================================
__global__ void fixup_kernel(const unsigned long long* __restrict__ sorted,
                             const unsigned int* __restrict__ prefix,
                             const unsigned int* __restrict__ hist,
                             const float* __restrict__ boxes,
                             unsigned long long* __restrict__ skeys,
                             float* __restrict__ sboxes) {
  int t = blockIdx.x * 256 + threadIdx.x;   // 2*7168
  int n = t / 7168;
  int s = t - n * 7168;
  const unsigned long long* srt = sorted + ((size_t)n << 13);
  unsigned long long key = srt[s];
  unsigned int hi = (unsigned int)(key >> 16);
  if (hi >= 0xFF800000u) {
    if (s < NPRE) skeys[(size_t)n * NPRE + s] = key;
    return;
  }
  unsigned int b = (unsigned int)(key >> 32);
  unsigned int st = prefix[((size_t)n << 16) + b];
  if (st >= (unsigned)NPRE) return;
  unsigned int cnt = hist[((size_t)n << 16) + b];
  unsigned int r = 0;
  if (cnt > 1) {
    for (unsigned int j = 0; j < cnt; j++) r += (srt[st + j] < key) ? 1u : 0u;
  }
  unsigned int pos = st + r;
  if (pos < (unsigned)NPRE) {
    skeys[(size_t)n * NPRE + pos] = key;
    int k = (int)(key & 0xFFFFull);
    float4 bx = *(const float4*)(boxes + (((size_t)n * NANCH) + k) * 4);
    *(float4*)(sboxes + ((size_t)n * NPRE + pos) * 4) = bx;
  }
}

// =====================================================================
// NMS phase A: pairwise suppression bitmask (+ fused validity mask)
// =====================================================================
__global__ __launch_bounds__(64) void nms_mask_kernel(
    const float* __restrict__ sboxes,
    const unsigned long long* __restrict__ skeys,
    unsigned long long* __restrict__ vmask,
    unsigned long long* __restrict__ mask) {
  int n = blockIdx.z;
  int ib = blockIdx.x, jb = blockIdx.y;
  int lane = threadIdx.x;
  __shared__ __align__(16) float jbox[64][4];
  int j = jb * 64 + lane;
  float4 bj4 = (j < NPRE)
                   ? *(const float4*)(sboxes + ((size_t)n * NPRE + j) * 4)
                   : float4{0.f, 0.f, 0.f, 0.f};
  *(float4*)jbox[lane] = bj4;
  __syncthreads();
  if (jb == 0) {
    int idx = ib * 64 + lane;
    bool ok = false;
    if (idx < NPRE) {
      unsigned int khi = (unsigned int)(skeys[(size_t)n * NPRE + idx] >> 16);
      ok = khi < 0xFF800000u;
    }
    unsigned long long m = __ballot(ok);
    if (lane == 0) vmask[(size_t)n * 94 + ib] = m;
  }
  int i = ib * 64 + lane;
  if (i >= NPRE) return;
  float4 bi = *(const float4*)(sboxes + ((size_t)n * NPRE + i) * 4);
  float ay1 = bi.x, ax1 = bi.y, ay2 = bi.z, ax2 = bi.w;
  float areaA = __fmul_rn(__fsub_rn(ay2, ay1), __fsub_rn(ax2, ax1));
  unsigned long long bits = 0ull;
#pragma unroll 8
  for (int l = 0; l < 64; l++) {
    float4 bj = *(const float4*)jbox[l];
    float ty1 = fmaxf(ay1, bj.x), tx1 = fmaxf(ax1, bj.y);
    float ty2 = fminf(ay2, bj.z), tx2 = fminf(ax2, bj.w);
    float wh0 = fmaxf(__fsub_rn(ty2, ty1), 0.f);
    float wh1 = fmaxf(__fsub_rn(tx2, tx1), 0.f);
    float inter = __fmul_rn(wh0, wh1);
    float areaB = __fmul_rn(__fsub_rn(bj.z, bj.x), __fsub_rn(bj.w, bj.y));
    float den = __fadd_rn(__fsub_rn(__fadd_rn(areaA, areaB), inter), 1e-9f);
    float iou = __fdiv_rn(inter, den);
    if (iou > 0.7f) bits |= (1ull << l);
  }
  mask[((size_t)n * NPRE + i) * 94 + jb] = bits;
}

// =====================================================================
// NMS phase B (R9/R11-proven): sequential greedy reduce, one wave/batch
// =====================================================================
__global__ __launch_bounds__(64) void nms_reduce_kernel(
    const unsigned long long* __restrict__ mask,
    const unsigned long long* __restrict__ vmask,
    const float* __restrict__ sboxes, float* __restrict__ out) {
  int n = blockIdx.x;
  int lane = threadIdx.x;
  __shared__ int kept[NPOST];
  __shared__ int s_count;

  unsigned long long rlo = ~vmask[(size_t)n * 94 + lane];
  unsigned long long rhi = (64 + lane < 94) ? ~vmask[(size_t)n * 94 + 64 + lane]
                                            : ~0ull;
  int count = 0;
  for (int c = 0; c < 94 && count < NPOST; c++) {
    unsigned long long curw =
        (c < 64) ? __shfl(rlo, c) : __shfl(rhi, c - 64);
    unsigned long long cand = ~curw;
    while (cand != 0ull && count < NPOST) {
      int b = __builtin_ctzll(cand);
      int i = c * 64 + b;
      if (lane == 0) kept[count] = i;
      count++;
      const unsigned long long* row = mask + ((size_t)n * NPRE + i) * 94;
      unsigned long long r0 = row[lane];
      unsigned long long r1 = (64 + lane < 94) ? row[64 + lane] : 0ull;
      rlo |= r0; rhi |= r1;
      curw = (c < 64) ? __shfl(rlo, c) : __shfl(rhi, c - 64);
      cand = ~curw;
      cand &= (b == 63) ? 0ull : (~0ull << (b + 1));
    }
  }
  if (lane == 0) s_count = count;
  __syncthreads();
  count = s_count;

  float* rois = out + ROIS_OFF + (size_t)n * NPOST * 4;
  float* ridx = out + RIDX_OFF + (size_t)n * NPOST;
  for (int s = lane; s < NPOST; s += 64) {
    float4 v = {0.f, 0.f, 0.f, 0.f};
    if (s < count) {
      int i = kept[s];
      v = *(const float4*)(sboxes + ((size_t)n * NPRE + i) * 4);
    }
    *(float4*)(rois + (size_t)s * 4) = v;
    ridx[s] = (float)n;
  }
}

// =====================================================================
extern "C" void kernel_launch(void* const* d_in, const int* in_sizes, int n_in,
                              void* d_out, int out_size, void* d_ws,
                              size_t ws_size, hipStream_t stream) {
  const float* feat = (const float*)d_in[0];
  const float* w1 = (const float*)d_in[1];
  const float* b1 = (const float*)d_in[2];
  const float* sw = (const float*)d_in[3];
  const float* sb = (const float*)d_in[4];
  const float* lw = (const float*)d_in[5];
  const float* lb = (const float*)d_in[6];
  const int* pimh = (const int*)d_in[7];
  const int* pimw = (const int*)d_in[8];
  float* out = (float*)d_out;
  char* ws = (char*)d_ws;

  float* wt = (float*)(ws + WT_OFF);
  float* w54p = (float*)(ws + W54_OFF);
  float* hbuf = (float*)(ws + H_OFF);
  float* boxes = (float*)(ws + BOXES_OFF);
  unsigned long long* keys = (unsigned long long*)(ws + KEYS_OFF);
  unsigned int* hist = (unsigned int*)(ws + HIST_OFF);
  unsigned int* prefix = (unsigned int*)(ws + PREFIX_OFF);
  unsigned int* prefix_mut = (unsigned int*)(ws + PREFIXM_OFF);
  unsigned long long* sorted = (unsigned long long*)(ws + SORTED_OFF);
  unsigned long long* skeys = (unsigned long long*)(ws + SKEYS_OFF);
  float* sboxes = (float*)(ws + SBOXES_OFF);
  unsigned long long* vmask = (unsigned long long*)(ws + VMASK_OFF);
  unsigned long long* nmask = (unsigned long long*)(ws + MASK_OFF);

  hipMemsetAsync(ws + HIST_OFF, 0, 524288, stream);

  // w54p lives in the BOXES region: written here, consumed by heads,
  // then decode overwrites the region with boxes.
  prep_kernel<<<288, 1024, 0, stream>>>(w1, wt, lw, sw, w54p);
  conv1_kernel<<<dim3(128, 4), 256, 0, stream>>>(feat, wt, b1, hbuf);
  heads_kernel<<<128, 256, 0, stream>>>(hbuf, w54p, lb, sb, out);
  decode_kernel<<<288, 256, 0, stream>>>(out, pimh, pimw, boxes, keys, hist,
                                         out);
  scanfull_kernel<<<2, 1024, 0, stream>>>(hist, prefix, prefix_mut);
  scatter_kernel<<<288, 256, 0, stream>>>(keys, prefix_mut, sorted);
  fixup_kernel<<<56, 256, 0, stream>>>(sorted, prefix, hist, boxes, skeys,
                                       sboxes);
  // prefix/sorted dead; nmask overwrites offset 0
  nms_mask_kernel<<<dim3(94, 94, 2), 64, 0, stream>>>(sboxes, skeys, vmask,
                                                      nmask);
  nms_reduce_kernel<<<2, 64, 0, stream>>>(nmask, vmask, sboxes, out);
}